// Round 8
// baseline (356.788 us; speedup 1.0000x reference)
//
#include <hip/hip_runtime.h>
#include <hip/hip_bf16.h>
#include <math.h>

#define B_ 8
#define C_ 64
#define H_ 128
#define W_ 128
#define HW_ (H_*W_)
#define HP_ 130
#define WP_ 130
#define XPLANE_ (HP_*WP_*64)     // padded NHWC plane per batch (halfwords)

typedef __attribute__((ext_vector_type(8))) short bf16x8;
typedef __attribute__((ext_vector_type(4))) float f32x4;
typedef __attribute__((ext_vector_type(4))) unsigned int u32x4;

// ---------------------------------------------------------------------------
// Zero only the 1-px halo ring of the 3 padded NHWC planes.
// ---------------------------------------------------------------------------
__global__ __launch_bounds__(256)
void zero_halo_k(unsigned int* __restrict__ planes)
{
    const int blk = blockIdx.x;
    const int plane = blk >> 3, batch = blk & 7;
    unsigned int* base = planes + (size_t)plane*4326400 + (size_t)batch*(XPLANE_/2);
    for (int i = threadIdx.x; i < 516*32; i += 256){
        const int u = i & 31, p = i >> 5;
        int h, w;
        if (p < 130)      { h = 0;        w = p;       }
        else if (p < 260) { h = 129;      w = p - 130; }
        else if (p < 388) { h = p - 259;  w = 0;       }
        else              { h = p - 387;  w = 129;     }
        base[(size_t)(h*130 + w)*32 + u] = 0u;
    }
}

// ---------------------------------------------------------------------------
// x NCHW fp32 -> xTp padded NHWC bf16 (interior only; halo pre-zeroed).
// ---------------------------------------------------------------------------
__global__ __launch_bounds__(256)
void xpose_x_k(const float* __restrict__ x, __hip_bfloat16* __restrict__ xTp)
{
    __shared__ float tile[64][65];
    const int tid = threadIdx.x;
    const int w0 = blockIdx.x*64, h = blockIdx.y, b = blockIdx.z;
    const float* xb = x + (size_t)b*64*HW_;
    for (int i = tid; i < 4096; i += 256){
        const int c = i >> 6, px = i & 63;
        tile[c][px] = xb[(size_t)c*HW_ + h*W_ + w0 + px];
    }
    __syncthreads();
    __hip_bfloat16* ob = xTp + (size_t)b*XPLANE_;
    for (int i = tid; i < 512; i += 256){
        const int px = i >> 3, cs = i & 7;
        union { bf16x8 v; __hip_bfloat16 h8[8]; } R;
#pragma unroll
        for (int j=0;j<8;j++) R.h8[j] = __float2bfloat16(tile[cs*8+j][px]);
        *(bf16x8*)&ob[((size_t)(h+1)*WP_ + (w0+px+1))*64 + cs*8] = R.v;
    }
}

// ---------------------------------------------------------------------------
// Fragment-order weight pack: w fp32 [O][64][9] ->
//   wf[(k*NC+cob)*8 + g*2+s][lane=khi*16+l15][j=0..7]
//     = bf16( w[co = cob*64+g*16+l15][c = s*32+khi*8+j][k] ), 0 if co>=O_real.
// A-fragment load in the GEMM kernels becomes a fully coalesced
// 16B/lane read at  wf + frag*1KB + lane*16B  (L1-broadcast across waves).
// ---------------------------------------------------------------------------
__device__ __forceinline__ void pack_one(const float* __restrict__ w,
                                         __hip_bfloat16* __restrict__ wf,
                                         int O_real, int nc, int idx)
{
    if (idx >= nc*36864) return;
    const int j = idx & 7, lane = (idx>>3)&63, f = (idx>>9)&7, t = idx>>12;
    const int k = t/nc, cob = t - k*nc;
    const int g = f>>1, s = f&1, l15 = lane&15, khi = lane>>4;
    const int co = cob*64 + g*16 + l15;
    const int c  = s*32 + khi*8 + j;
    const float v = (co < O_real) ? w[((size_t)co*64 + c)*9 + k] : 0.f;
    wf[idx] = __float2bfloat16(v);
}

__global__ __launch_bounds__(256)
void pack_all_k(const float* __restrict__ w1, const float* __restrict__ w2,
                const float* __restrict__ w3, const float* __restrict__ wa,
                const float* __restrict__ wd,
                __hip_bfloat16* __restrict__ wf1, __hip_bfloat16* __restrict__ wf2,
                __hip_bfloat16* __restrict__ wf3, __hip_bfloat16* __restrict__ wfa,
                __hip_bfloat16* __restrict__ wfd)
{
    const int bx = blockIdx.x, tid = threadIdx.x;
    if      (bx < 144) pack_one(w1, wf1,  64, 1, bx*256 + tid);
    else if (bx < 288) pack_one(w2, wf2,  64, 1, (bx-144)*256 + tid);
    else if (bx < 432) pack_one(w3, wf3,  36, 1, (bx-288)*256 + tid);
    else if (bx < 720) pack_one(wa, wfa, 128, 2, (bx-432)*256 + tid);
    else               pack_one(wd, wfd, 128, 2, (bx-720)*256 + tid);
}

// ---------------------------------------------------------------------------
// Implicit-GEMM 3x3 conv via MFMA. ZERO LDS, ZERO barriers: A-fragments are
// coalesced 16B/lane loads from the fragment-packed weights; B = direct 16B
// NHWC loads at the tap-shifted position. Fully unrolled k-loop.
// ---------------------------------------------------------------------------
enum OutMode { OUT_NHWC_PAD_RELU, OUT_NCHW_F32, OUT_NCHW_BF16 };

template<int G, int NC, int CO_TOT, OutMode MODE>
__global__ __launch_bounds__(256, 4)
void conv_mfma_k(const __hip_bfloat16* __restrict__ xT,
                 const __hip_bfloat16* __restrict__ wf,
                 void* __restrict__ outp)
{
    const int tid = threadIdx.x, lane = tid & 63, wid = tid >> 6;
    const int l15 = lane & 15, khi = lane >> 4;
    const int ow0 = blockIdx.x*64, oh = blockIdx.y;
    const int b = blockIdx.z & 7, cob = blockIdx.z >> 3;
    const int px = wid*16 + l15;
    const __hip_bfloat16* xb = xT + (size_t)b*XPLANE_;

    f32x4 acc[G];
    const f32x4 vz = {0.f,0.f,0.f,0.f};
#pragma unroll
    for (int g=0; g<G; ++g) acc[g] = vz;

#pragma unroll
    for (int k=0; k<9; ++k){
        const int dy = k/3 - 1, dxk = k%3 - 1;
        const int base = ((oh+1+dy)*WP_ + (ow0+px+1+dxk))*64;
        const __hip_bfloat16* wfk = wf + (size_t)(k*NC + cob)*8*512 + lane*8;
#pragma unroll
        for (int s=0; s<2; ++s){
            const bf16x8 bfr = *(const bf16x8*)&xb[base + s*32 + khi*8];
#pragma unroll
            for (int g=0; g<G; ++g){
                const bf16x8 afr = *(const bf16x8*)&wfk[(size_t)(g*2+s)*512];
                acc[g] = __builtin_amdgcn_mfma_f32_16x16x32_bf16(afr, bfr, acc[g], 0,0,0);
            }
        }
    }
    // ---- epilogue ----
    if (MODE == OUT_NHWC_PAD_RELU){
        __hip_bfloat16* ob = (__hip_bfloat16*)outp + (size_t)b*XPLANE_;
        const size_t orow = ((size_t)(oh+1)*WP_ + (ow0+px+1))*64;
#pragma unroll
        for (int g=0; g<G; ++g){
            union { short4 s4; __hip_bfloat16 h[4]; } o4;
#pragma unroll
            for (int r=0;r<4;r++) o4.h[r] = __float2bfloat16(fmaxf(acc[g][r], 0.f));
            *(short4*)&ob[orow + g*16 + khi*4] = o4.s4;
        }
    } else if (MODE == OUT_NCHW_F32){
        float* ob = (float*)outp;
#pragma unroll
        for (int g=0; g<G; ++g)
#pragma unroll
            for (int r=0;r<4;r++){
                const int co = cob*64 + g*16 + khi*4 + r;
                if (co < CO_TOT)
                    ob[(((size_t)b*CO_TOT + co)*H_ + oh)*W_ + ow0 + px] = acc[g][r];
            }
    } else {
        __hip_bfloat16* ob = (__hip_bfloat16*)outp;
#pragma unroll
        for (int g=0; g<G; ++g)
#pragma unroll
            for (int r=0;r<4;r++){
                const int co = cob*64 + g*16 + khi*4 + r;
                ob[(((size_t)b*CO_TOT + co)*H_ + oh)*W_ + ow0 + px] = __float2bfloat16(acc[g][r]);
            }
    }
}

// ---------------------------------------------------------------------------
// 4-corner bilinear blend of 8 consecutive channels (NHWC bf16) -> bf16x8.
// ---------------------------------------------------------------------------
__device__ __forceinline__ bf16x8 blend4(const __hip_bfloat16* __restrict__ xb,
                                         int a00, int dxo, int dro, float4 w)
{
    const u32x4 q00 = *(const u32x4*)(xb + a00);
    const u32x4 q01 = *(const u32x4*)(xb + a00 + dxo);
    const u32x4 q10 = *(const u32x4*)(xb + a00 + dro);
    const u32x4 q11 = *(const u32x4*)(xb + a00 + dro + dxo);
    union { bf16x8 v; __hip_bfloat16 h[8]; } R;
#pragma unroll
    for (int p=0;p<4;++p){
        const float l00 = __uint_as_float(q00[p]<<16), h00 = __uint_as_float(q00[p]&0xFFFF0000u);
        const float l01 = __uint_as_float(q01[p]<<16), h01 = __uint_as_float(q01[p]&0xFFFF0000u);
        const float l10 = __uint_as_float(q10[p]<<16), h10 = __uint_as_float(q10[p]&0xFFFF0000u);
        const float l11 = __uint_as_float(q11[p]<<16), h11 = __uint_as_float(q11[p]&0xFFFF0000u);
        R.h[2*p  ] = __float2bfloat16(w.x*l00 + w.y*l01 + w.z*l10 + w.w*l11);
        R.h[2*p+1] = __float2bfloat16(w.x*h00 + w.y*h01 + w.z*h10 + w.w*h11);
    }
    return R.v;
}

// ---------------------------------------------------------------------------
struct Meta { int a00, dxo, dro; float4 w4; };

__device__ __forceinline__ Meta mkmeta(int oh, int ow0, int px, int k,
                                       float oy, float ox)
{
    const int kr = k/3, kc = k - 3*kr;
    const float py  = (float)(oh  - 1 + kr) + oy;
    const float pxx = (float)(ow0 + px - 1 + kc) + ox;
    const float y0f = floorf(py), x0f = floorf(pxx);
    const float ay = py - y0f, ax = pxx - x0f;
    const int y0 = (int)y0f, x0 = (int)x0f;
    const int y1 = y0 + 1,   x1 = x0 + 1;
    const float my0 = (y0 >= 0 && y0 < H_) ? 1.f : 0.f;
    const float my1 = (y1 >= 0 && y1 < H_) ? 1.f : 0.f;
    const float mx0 = (x0 >= 0 && x0 < W_) ? 1.f : 0.f;
    const float mx1 = (x1 >= 0 && x1 < W_) ? 1.f : 0.f;
    const int y0c = min(max(y0,0),H_-1), y1c = min(max(y1,0),H_-1);
    const int x0c = min(max(x0,0),W_-1), x1c = min(max(x1,0),W_-1);
    const float wy0 = my0*(1.f-ay), wy1 = my1*ay;
    const float wx0 = mx0*(1.f-ax), wx1 = mx1*ax;
    Meta m;
    m.a00 = ((y0c+1)*WP_ + (x0c+1))*64;
    m.dxo = (x1c-x0c)*64;
    m.dro = (y1c-y0c)*WP_*64;
    m.w4  = make_float4(wy0*wx0, wy0*wx1, wy1*wx0, wy1*wx1);
    return m;
}

// ---------------------------------------------------------------------------
// Fused deformable conv (MFMA) + softmax attention, v5:
// ZERO LDS, ZERO barriers. Weights read as coalesced fragment-packed loads;
// B-fragments built in registers from NHWC corner gathers. Fully unrolled
// (k,dk) loop -> compiler pipelines loads across taps with no sync points.
// ---------------------------------------------------------------------------
__global__ __launch_bounds__(256, 4)
void deform_att_k(const __hip_bfloat16* __restrict__ xT,
                  const float* __restrict__ off,
                  const __hip_bfloat16* __restrict__ att,
                  const __hip_bfloat16* __restrict__ wfd,  // fragment-packed
                  float* __restrict__ out)
{
    const int tid = threadIdx.x, lane = tid & 63, wid = tid >> 6;
    const int l15 = lane & 15, khi = lane >> 4;
    const int ow0 = blockIdx.x*64, oh = blockIdx.y, b = blockIdx.z;
    const int px = wid*16 + l15;
    const __hip_bfloat16* xb = xT + (size_t)b*XPLANE_;
    const float* offb = off + (size_t)b*36*HW_ + (size_t)oh*W_ + ow0 + px;

    f32x4 acc[2][4];
    const f32x4 vz = {0.f,0.f,0.f,0.f};
#pragma unroll
    for (int d=0; d<2; ++d)
#pragma unroll
        for (int g=0; g<4; ++g) acc[d][g] = vz;

#pragma unroll
    for (int k=0; k<9; ++k){
#pragma unroll
        for (int dk=0; dk<2; ++dk){
            const float oy = offb[(size_t)(dk*18 + 2*k    )*HW_];
            const float ox = offb[(size_t)(dk*18 + 2*k + 1)*HW_];
            const Meta m = mkmeta(oh, ow0, px, k, oy, ox);
            const __hip_bfloat16* wfk =
                wfd + (size_t)(k*2 + dk)*8*512 + lane*8;
#pragma unroll
            for (int s=0; s<2; ++s){
                const bf16x8 bfr = blend4(xb, m.a00 + s*32 + khi*8, m.dxo, m.dro, m.w4);
#pragma unroll
                for (int g=0; g<4; ++g){
                    const bf16x8 afr = *(const bf16x8*)&wfk[(size_t)(g*2+s)*512];
                    acc[dk][g] = __builtin_amdgcn_mfma_f32_16x16x32_bf16(afr, bfr, acc[dk][g], 0,0,0);
                }
            }
        }
    }
    // ---- epilogue: softmax over the 2 dynamic branches + write ----
#pragma unroll
    for (int g=0; g<4; ++g)
#pragma unroll
        for (int r=0; r<4; ++r){
            const int co = g*16 + khi*4 + r;
            const float a0 = __bfloat162float(att[(((size_t)b*128      + co)*H_ + oh)*W_ + ow0 + px]);
            const float a1 = __bfloat162float(att[(((size_t)b*128 + 64 + co)*H_ + oh)*W_ + ow0 + px]);
            const float f0 = 1.f / (1.f + __expf(a1 - a0));
            out[(((size_t)b*64 + co)*H_ + oh)*W_ + ow0 + px] =
                acc[0][g][r]*f0 + acc[1][g][r]*(1.f - f0);
        }
}

// ---------------------------------------------------------------------------
extern "C" void kernel_launch(void* const* d_in, const int* in_sizes, int n_in,
                              void* d_out, int out_size, void* d_ws, size_t ws_size,
                              hipStream_t stream)
{
    const float* x  = (const float*)d_in[0];
    const float* w1 = (const float*)d_in[1];
    const float* w2 = (const float*)d_in[2];
    const float* w3 = (const float*)d_in[3];
    const float* wa = (const float*)d_in[4];
    const float* wd = (const float*)d_in[5];
    float* out = (float*)d_out;

    // ---- workspace layout (halfword units for bf16 regions) ----
    __hip_bfloat16* xTp  = (__hip_bfloat16*)d_ws;       // 8,652,800
    __hip_bfloat16* m1Tp = xTp  + (size_t)8652800;      // 8,652,800
    __hip_bfloat16* m2Tp = m1Tp + (size_t)8652800;      // 8,652,800
    __hip_bfloat16* wf1  = m2Tp + (size_t)8652800;      // 36864
    __hip_bfloat16* wf2  = wf1  + 36864;                // 36864
    __hip_bfloat16* wf3  = wf2  + 36864;                // 36864
    __hip_bfloat16* wfa  = wf3  + 36864;                // 73728
    __hip_bfloat16* wfd  = wfa  + 73728;                // 73728
    float*          offs = (float*)(wfd + 73728);       // 8*36*128*128 fp32
    __hip_bfloat16* att16 = m1Tp;   // aliases m1Tp+m2Tp (both dead by then)

    const dim3 blk(256);
    // halo-only zeroing of the 3 padded planes
    zero_halo_k<<<dim3(24), blk, 0, stream>>>((unsigned int*)xTp);
    // layout transforms
    xpose_x_k<<<dim3(2,128,8), blk, 0, stream>>>(x, xTp);
    pack_all_k<<<dim3(1008), blk, 0, stream>>>(w1,w2,w3,wa,wd, wf1,wf2,wf3,wfa,wfd);
    // conv chain (implicit-GEMM MFMA, barrier-free, LDS-free)
    conv_mfma_k<4, 1,  64, OUT_NHWC_PAD_RELU><<<dim3(2,128,8),  blk, 0, stream>>>(xTp,  wf1, m1Tp);
    conv_mfma_k<4, 1,  64, OUT_NHWC_PAD_RELU><<<dim3(2,128,8),  blk, 0, stream>>>(m1Tp, wf2, m2Tp);
    conv_mfma_k<3, 1,  36, OUT_NCHW_F32     ><<<dim3(2,128,8),  blk, 0, stream>>>(m2Tp, wf3, offs);
    conv_mfma_k<4, 2, 128, OUT_NCHW_BF16    ><<<dim3(2,128,16), blk, 0, stream>>>(xTp,  wfa, att16);
    // fused deformable conv + attention (v5: no LDS, no barriers)
    deform_att_k<<<dim3(2,128,8), blk, 0, stream>>>(xTp, offs, att16, wfd, out);
}